// Round 6
// baseline (269.014 us; speedup 1.0000x reference)
//
#include <hip/hip_runtime.h>

#define K 64
#define S_CHUNK 32
#define W_BURN 128
#define BATCH 16

typedef __attribute__((ext_vector_type(4))) _Float16 half4;
typedef __attribute__((ext_vector_type(4))) float f32x4;

__device__ __forceinline__ float waveReduceSum(float v) {
#pragma unroll
    for (int off = 32; off > 0; off >>= 1) v += __shfl_xor(v, off, 64);
    return v;
}

// ws layout (float offsets)
#define WS_P     0      // P row-major [64][64] f32
#define WS_PI    4096
#define WS_UTT0  4160
#define WS_ISG   4224   // 1/sigma
#define WS_NNU   4288   // -mu/sigma
#define WS_L2N   4352   // log2(1/(sigma*sqrt(2pi)))

__global__ __launch_bounds__(64) void hmm_setup(
    const float* __restrict__ y, const float* __restrict__ logits,
    const float* __restrict__ mu, const float* __restrict__ log_sigma,
    float* __restrict__ out, float* __restrict__ ws, int T)
{
    __shared__ float P[K][K];
    __shared__ float pib[K];
    const int k = threadIdx.x;

    float row[K]; float m = -3.4e38f;
#pragma unroll
    for (int i = 0; i < K; ++i) { row[i] = logits[k*K + i]; m = fmaxf(m, row[i]); }
    float s = 0.f;
#pragma unroll
    for (int i = 0; i < K; ++i) { row[i] = __expf(row[i] - m); s += row[i]; }
    float inv = 1.0f / s;
#pragma unroll
    for (int i = 0; i < K; ++i) { float p = row[i]*inv; P[k][i] = p; ws[WS_P + k*K + i] = p; }
    __syncthreads();

    pib[k] = 1.0f/64.0f;
    __syncthreads();
    for (int it = 0; it < 64; ++it) {
        float acc = 0.f;
#pragma unroll
        for (int j = 0; j < K; ++j) acc += pib[j]*P[j][k];   // (pi^T P)_k
        float tot = waveReduceSum(acc);
        acc /= tot;
        __syncthreads();
        pib[k] = acc;
        __syncthreads();
    }
    float pi_k = pib[k];

    float mu_k = mu[k];
    float isg = __expf(-log_sigma[k]);            // 1/sigma
    float inorm = isg * 0.39894228040143267f;     // 1/(sigma*sqrt(2pi))

    ws[WS_PI  + k] = pi_k;
    ws[WS_ISG + k] = isg;
    ws[WS_NNU + k] = -mu_k * isg;
    ws[WS_L2N + k] = __log2f(inorm);

    float y0 = y[0];
    float z = (y0 - mu_k) * isg;
    float g0 = __expf(-0.5f*z*z) * inorm;
    float num = pi_k * g0;
    float ft0 = waveReduceSum(num);
    float utt0 = num / ft0;
    ws[WS_UTT0 + k] = utt0;

    out[k] = pi_k;                       // ut[0]
    out[(size_t)T*K + k] = utt0;         // unorm[0]
    if (k == 0) out[(size_t)2*T*K] = ft0;// ft[0]
}

// One wave = 16 chunks (MFMA columns). S_CHUNK=32 so that 1954 waves give
// ~2 waves/SIMD: a co-resident wave issues during this wave's stall cycles
// (R5 lesson: at 0.5 waves/SIMD the kernel is pure exposed latency; pipeline
// restructuring was neutral). Lagged pow2 normalization keeps the reduce off
// the beta chain; MFMA split into 4 independent kb-chains (depth-1).
__global__ __launch_bounds__(64) void hmm_scan(
    const float* __restrict__ y, const float* __restrict__ ws,
    float* __restrict__ out, int T)
{
    const int lane = threadIdx.x;
    const int c = lane & 15;          // chunk slot / matrix column
    const int q = lane >> 4;          // lane group
    const int cg = blockIdx.x * BATCH + c;
    const int t0 = cg * S_CHUNK;

    // A fragments: A(nb,kb)[i][kk] = P[16kb+kk][16nb+i]
    half4 a[4][4];
#pragma unroll
    for (int nb = 0; nb < 4; ++nb)
#pragma unroll
        for (int kb = 0; kb < 4; ++kb)
#pragma unroll
            for (int j = 0; j < 4; ++j)
                a[nb][kb][j] = (_Float16)ws[WS_P + (16*kb + 4*q + j)*K + 16*nb + c];

    f32x4 isg_[4], nnu_[4], l2n_[4];
#pragma unroll
    for (int nb = 0; nb < 4; ++nb)
#pragma unroll
        for (int r = 0; r < 4; ++r) {
            int s = 16*nb + 4*q + r;
            isg_[nb][r] = ws[WS_ISG + s];
            nnu_[nb][r] = ws[WS_NNU + s];
            l2n_[nb][r] = ws[WS_L2N + s];
        }

    half4 bfr[4], u0h[4];
#pragma unroll
    for (int kb = 0; kb < 4; ++kb)
#pragma unroll
        for (int j = 0; j < 4; ++j) {
            int s = 16*kb + 4*q + j;
            bfr[kb][j] = (_Float16)ws[WS_PI + s];
            u0h[kb][j] = (_Float16)ws[WS_UTT0 + s];
        }

    const int tlo = (cg == 0) ? 1 : 0;
    int tcur = t0 - W_BURN;

    float* po = out + (size_t)t0 * K + 4*q;
    float* pu = po + (size_t)T * K;
    float* pf = out + (size_t)2 * T * K + t0;

    // pipeline state: h = in-lane partial sum of nb_{t-1}; rmP = rcp(mant(st_{t-2}))
    float h = 0.25f;      // finalizes to st = 1 (beta = pi, sum 1)
    float rmP = 1.0f;
    f32x4 nbP[4] = {{0.f,0.f,0.f,0.f},{0.f,0.f,0.f,0.f},
                    {0.f,0.f,0.f,0.f},{0.f,0.f,0.f,0.f}};

    int ib = min(max(tcur, 0), T - 4);
    f32x4 yv = *(const f32x4*)(y + ib);

#define STEP(OUTC, OUTPV, YCUR) do {                                           \
    /* 1. MFMA: 4 independent kb-chains (matrix-pipe dep depth 1) */           \
    f32x4 ac0_[4] = {{0.f,0.f,0.f,0.f},{0.f,0.f,0.f,0.f},                      \
                     {0.f,0.f,0.f,0.f},{0.f,0.f,0.f,0.f}};                     \
    f32x4 ac1_[4] = {{0.f,0.f,0.f,0.f},{0.f,0.f,0.f,0.f},                      \
                     {0.f,0.f,0.f,0.f},{0.f,0.f,0.f,0.f}};                     \
    f32x4 ac2_[4] = {{0.f,0.f,0.f,0.f},{0.f,0.f,0.f,0.f},                      \
                     {0.f,0.f,0.f,0.f},{0.f,0.f,0.f,0.f}};                     \
    f32x4 ac3_[4] = {{0.f,0.f,0.f,0.f},{0.f,0.f,0.f,0.f},                      \
                     {0.f,0.f,0.f,0.f},{0.f,0.f,0.f,0.f}};                     \
    _Pragma("unroll")                                                          \
    for (int nb_ = 0; nb_ < 4; ++nb_)                                          \
        ac0_[nb_] = __builtin_amdgcn_mfma_f32_16x16x16f16(a[nb_][0], bfr[0], ac0_[nb_], 0,0,0); \
    _Pragma("unroll")                                                          \
    for (int nb_ = 0; nb_ < 4; ++nb_)                                          \
        ac1_[nb_] = __builtin_amdgcn_mfma_f32_16x16x16f16(a[nb_][1], bfr[1], ac1_[nb_], 0,0,0); \
    _Pragma("unroll")                                                          \
    for (int nb_ = 0; nb_ < 4; ++nb_)                                          \
        ac2_[nb_] = __builtin_amdgcn_mfma_f32_16x16x16f16(a[nb_][2], bfr[2], ac2_[nb_], 0,0,0); \
    _Pragma("unroll")                                                          \
    for (int nb_ = 0; nb_ < 4; ++nb_)                                          \
        ac3_[nb_] = __builtin_amdgcn_mfma_f32_16x16x16f16(a[nb_][3], bfr[3], ac3_[nb_], 0,0,0); \
    /* 2. lag-finalize st_{t-1} (overlaps MFMA) */                             \
    float s1_ = h + __shfl_xor(h, 16, 64);                                     \
    float stP_ = s1_ + __shfl_xor(s1_, 32, 64);                                \
    float rsP_ = __builtin_amdgcn_rcpf(stP_);                                  \
    float ftprev_ = stP_ * rmP;                                                \
    unsigned ub_ = __float_as_uint(stP_);                                      \
    float xf_ = (float)(127 - (int)((ub_ >> 23) & 255u));                      \
    float mant_ = __uint_as_float((ub_ & 0x007fffffu) | 0x3f800000u);          \
    float rmN_ = __builtin_amdgcn_rcpf(mant_);                                 \
    /* 3. emissions with folded 2^xf scale */                                  \
    f32x4 g_[4];                                                               \
    _Pragma("unroll")                                                          \
    for (int nb_ = 0; nb_ < 4; ++nb_) {                                        \
        f32x4 z_ = YCUR * isg_[nb_] + nnu_[nb_];                               \
        f32x4 ag_ = z_*z_*(-0.72134752f) + l2n_[nb_] + xf_;                    \
        _Pragma("unroll")                                                      \
        for (int r_ = 0; r_ < 4; ++r_) g_[nb_][r_] = __builtin_amdgcn_exp2f(ag_[r_]); \
    }                                                                          \
    /* 4. lagged stores: unorm_{t-1}, ft_{t-1} */                              \
    if (OUTPV) {                                                               \
        const bool pp_ = ((tcur-1) >= tlo) & ((tcur-1) < T);                   \
        if (pp_) {                                                             \
            _Pragma("unroll")                                                  \
            for (int nb_ = 0; nb_ < 4; ++nb_)                                  \
                *(f32x4*)(pu - K + 16*nb_) = nbP[nb_] * rsP_;                  \
            if (lane < 16) pf[-1] = ftprev_;                                   \
        }                                                                      \
    }                                                                          \
    /* 5. chain: tree-sum acc -> nb -> cvt */                                  \
    f32x4 acc_[4], nbv_[4];                                                    \
    _Pragma("unroll")                                                          \
    for (int nb_ = 0; nb_ < 4; ++nb_)                                          \
        acc_[nb_] = (ac0_[nb_] + ac1_[nb_]) + (ac2_[nb_] + ac3_[nb_]);         \
    _Pragma("unroll")                                                          \
    for (int nb_ = 0; nb_ < 4; ++nb_) nbv_[nb_] = acc_[nb_] * g_[nb_];         \
    _Pragma("unroll")                                                          \
    for (int kb_ = 0; kb_ < 4; ++kb_) {                                        \
        auto lo_ = __builtin_amdgcn_cvt_pkrtz(nbv_[kb_][0], nbv_[kb_][1]);     \
        auto hi_ = __builtin_amdgcn_cvt_pkrtz(nbv_[kb_][2], nbv_[kb_][3]);     \
        bfr[kb_][0] = (_Float16)lo_[0]; bfr[kb_][1] = (_Float16)lo_[1];        \
        bfr[kb_][2] = (_Float16)hi_[0]; bfr[kb_][3] = (_Float16)hi_[1];        \
    }                                                                          \
    /* 6. current ut store (off-chain) */                                      \
    if (OUTC) {                                                                \
        const bool pc_ = (tcur >= tlo) & (tcur < T);                           \
        if (pc_) {                                                             \
            _Pragma("unroll")                                                  \
            for (int nb_ = 0; nb_ < 4; ++nb_)                                  \
                *(f32x4*)(po + 16*nb_) = acc_[nb_] * rsP_;                     \
        }                                                                      \
    }                                                                          \
    /* 7. in-lane tree partial sum for st_t */                                 \
    {                                                                          \
        f32x4 sA_ = nbv_[0] + nbv_[1];                                         \
        f32x4 sB_ = nbv_[2] + nbv_[3];                                         \
        f32x4 sC_ = sA_ + sB_;                                                 \
        h = (sC_[0] + sC_[1]) + (sC_[2] + sC_[3]);                             \
    }                                                                          \
    nbP[0]=nbv_[0]; nbP[1]=nbv_[1]; nbP[2]=nbv_[2]; nbP[3]=nbv_[3];            \
    rmP = rmN_;                                                                \
    if (OUTC) { po += K; pu += K; pf += 1; }                                   \
    ++tcur;                                                                    \
} while (0)

    // burn-in: no stores, lag-scale machinery active
#pragma unroll 1
    for (int gi = 0; gi < W_BURN/4; ++gi) {
        int ibn = min(max(tcur + 4, 0), T - 4);
        f32x4 yn = *(const f32x4*)(y + ibn);
        STEP(0,0, yv[0]); STEP(0,0, yv[1]); STEP(0,0, yv[2]); STEP(0,0, yv[3]);
        yv = yn;
    }
    // first output group (peeled: chunk-0 state override after its t=0 step)
    {
        int ibn = min(max(tcur + 4, 0), T - 4);
        f32x4 yn = *(const f32x4*)(y + ibn);
        STEP(1,0, yv[0]);
        if (cg == 0) {
            bfr[0]=u0h[0]; bfr[1]=u0h[1]; bfr[2]=u0h[2]; bfr[3]=u0h[3];
            h = 0.25f;   // st_0 finalizes to 1 (utt0 sums to 1)
        }
        STEP(1,1, yv[1]); STEP(1,1, yv[2]); STEP(1,1, yv[3]);
        yv = yn;
    }
#pragma unroll 1
    for (int gi = 1; gi < S_CHUNK/4; ++gi) {
        int ibn = min(max(tcur + 4, 0), T - 4);
        f32x4 yn = *(const f32x4*)(y + ibn);
        STEP(1,1, yv[0]); STEP(1,1, yv[1]); STEP(1,1, yv[2]); STEP(1,1, yv[3]);
        yv = yn;
    }
#undef STEP

    // epilogue: finalize + store unorm/ft of the last step
    {
        float s1 = h + __shfl_xor(h, 16, 64);
        float stL = s1 + __shfl_xor(s1, 32, 64);
        float rsL = __builtin_amdgcn_rcpf(stL);
        float ftL = stL * rmP;
        const bool pp = ((tcur-1) >= tlo) & ((tcur-1) < T);
        if (pp) {
#pragma unroll
            for (int nb = 0; nb < 4; ++nb)
                *(f32x4*)(pu - K + 16*nb) = nbP[nb] * rsL;
            if (lane < 16) pf[-1] = ftL;
        }
    }
}

extern "C" void kernel_launch(void* const* d_in, const int* in_sizes, int n_in,
                              void* d_out, int out_size, void* d_ws, size_t ws_size,
                              hipStream_t stream) {
    const float* y      = (const float*)d_in[0];
    const float* logits = (const float*)d_in[1];
    const float* mu     = (const float*)d_in[2];
    const float* lsig   = (const float*)d_in[3];
    float* out = (float*)d_out;
    float* ws  = (float*)d_ws;
    const int T = in_sizes[0];

    hmm_setup<<<1, 64, 0, stream>>>(y, logits, mu, lsig, out, ws, T);

    const int nch  = (T + S_CHUNK - 1) / S_CHUNK;
    const int nblk = (nch + BATCH - 1) / BATCH;
    hmm_scan<<<nblk, 64, 0, stream>>>(y, ws, out, T);
}

// Round 7
// 236.400 us; speedup vs baseline: 1.1380x; 1.1380x over previous
//
#include <hip/hip_runtime.h>

#define K 64
#define S_CHUNK 128
#define W_BURN 160
#define BATCH 16

typedef __attribute__((ext_vector_type(4))) _Float16 half4;
typedef __attribute__((ext_vector_type(4))) float f32x4;

__device__ __forceinline__ float waveReduceSum(float v) {
#pragma unroll
    for (int off = 32; off > 0; off >>= 1) v += __shfl_xor(v, off, 64);
    return v;
}

// ws layout (float offsets)
#define WS_P     0      // P row-major [64][64] f32
#define WS_PI    4096
#define WS_UTT0  4160
#define WS_ISG   4224   // 1/sigma
#define WS_NNU   4288   // -mu/sigma
#define WS_L2N   4352   // log2(1/(sigma*sqrt(2pi)))

__global__ __launch_bounds__(64) void hmm_setup(
    const float* __restrict__ y, const float* __restrict__ logits,
    const float* __restrict__ mu, const float* __restrict__ log_sigma,
    float* __restrict__ out, float* __restrict__ ws, int T)
{
    __shared__ float P[K][K];
    __shared__ float pib[K];
    const int k = threadIdx.x;

    float row[K]; float m = -3.4e38f;
#pragma unroll
    for (int i = 0; i < K; ++i) { row[i] = logits[k*K + i]; m = fmaxf(m, row[i]); }
    float s = 0.f;
#pragma unroll
    for (int i = 0; i < K; ++i) { row[i] = __expf(row[i] - m); s += row[i]; }
    float inv = 1.0f / s;
#pragma unroll
    for (int i = 0; i < K; ++i) { float p = row[i]*inv; P[k][i] = p; ws[WS_P + k*K + i] = p; }
    __syncthreads();

    pib[k] = 1.0f/64.0f;
    __syncthreads();
    for (int it = 0; it < 64; ++it) {
        float acc = 0.f;
#pragma unroll
        for (int j = 0; j < K; ++j) acc += pib[j]*P[j][k];   // (pi^T P)_k
        float tot = waveReduceSum(acc);
        acc /= tot;
        __syncthreads();
        pib[k] = acc;
        __syncthreads();
    }
    float pi_k = pib[k];

    float mu_k = mu[k];
    float isg = __expf(-log_sigma[k]);            // 1/sigma
    float inorm = isg * 0.39894228040143267f;     // 1/(sigma*sqrt(2pi))

    ws[WS_PI  + k] = pi_k;
    ws[WS_ISG + k] = isg;
    ws[WS_NNU + k] = -mu_k * isg;
    ws[WS_L2N + k] = __log2f(inorm);

    float y0 = y[0];
    float z = (y0 - mu_k) * isg;
    float g0 = __expf(-0.5f*z*z) * inorm;
    float num = pi_k * g0;
    float ft0 = waveReduceSum(num);
    float utt0 = num / ft0;
    ws[WS_UTT0 + k] = utt0;

    out[k] = pi_k;                       // ut[0]
    out[(size_t)T*K + k] = utt0;         // unorm[0]
    if (k == 0) out[(size_t)2*T*K] = ft0;// ft[0]
}

// One wave = 16 chunks. R4 structure (serial reduce, cached stores) with
// ONE change: __launch_bounds__(64, 1). R4-R6 analysis: at the default
// occupancy target the allocator capped VGPRs at 84 while the live set is
// ~170 values (P fragments + emission consts + accs), so it rematerialized
// them as ~16 L1 loads per step -> ~1700 cy/step of exposed load latency
// (VALUBusy 11%, MfmaUtil 4%, uniform cost even in store-free burn steps,
// no cross-wave overlap). Budget 512 VGPRs so everything stays resident;
// occupancy is irrelevant (489 waves < 1024 SIMDs).
__global__ __launch_bounds__(64, 1) void hmm_scan(
    const float* __restrict__ y, const float* __restrict__ ws,
    float* __restrict__ out, int T)
{
    const int lane = threadIdx.x;
    const int c = lane & 15;          // chunk slot / matrix column
    const int q = lane >> 4;          // lane group
    const int NCH = (T + S_CHUNK - 1) / S_CHUNK;
    (void)NCH;
    const int cg = blockIdx.x * BATCH + c;
    const int t0 = cg * S_CHUNK;

    // A fragments: A(nb,kb)[i][kk] = P[16kb+kk][16nb+i]
    half4 a[4][4];
#pragma unroll
    for (int nb = 0; nb < 4; ++nb)
#pragma unroll
        for (int kb = 0; kb < 4; ++kb)
#pragma unroll
            for (int j = 0; j < 4; ++j)
                a[nb][kb][j] = (_Float16)ws[WS_P + (16*kb + 4*q + j)*K + 16*nb + c];

    f32x4 isg_[4], nnu_[4], l2n_[4];
#pragma unroll
    for (int nb = 0; nb < 4; ++nb)
#pragma unroll
        for (int r = 0; r < 4; ++r) {
            int s = 16*nb + 4*q + r;
            isg_[nb][r] = ws[WS_ISG + s];
            nnu_[nb][r] = ws[WS_NNU + s];
            l2n_[nb][r] = ws[WS_L2N + s];
        }

    half4 bfr[4], u0h[4];
#pragma unroll
    for (int kb = 0; kb < 4; ++kb)
#pragma unroll
        for (int j = 0; j < 4; ++j) {
            int s = 16*kb + 4*q + j;
            bfr[kb][j] = (_Float16)ws[WS_PI + s];
            u0h[kb][j] = (_Float16)ws[WS_UTT0 + s];
        }

    const int tlo = (cg == 0) ? 1 : 0;
    int tcur = t0 - W_BURN;

    float* po = out + (size_t)t0 * K + 4*q;
    float* pu = po + (size_t)T * K;
    float* pf = out + (size_t)2 * T * K + t0;

    int ib = min(max(tcur, 0), T - 4);
    f32x4 yv = *(const f32x4*)(y + ib);

#define STEP(OUTP, YCUR) do {                                                  \
    f32x4 accA_[4] = {{0.f,0.f,0.f,0.f},{0.f,0.f,0.f,0.f},                     \
                      {0.f,0.f,0.f,0.f},{0.f,0.f,0.f,0.f}};                    \
    f32x4 accB_[4] = {{0.f,0.f,0.f,0.f},{0.f,0.f,0.f,0.f},                     \
                      {0.f,0.f,0.f,0.f},{0.f,0.f,0.f,0.f}};                    \
    _Pragma("unroll")                                                          \
    for (int nb_ = 0; nb_ < 4; ++nb_)                                          \
        accA_[nb_] = __builtin_amdgcn_mfma_f32_16x16x16f16(a[nb_][0], bfr[0], accA_[nb_], 0,0,0); \
    _Pragma("unroll")                                                          \
    for (int nb_ = 0; nb_ < 4; ++nb_)                                          \
        accB_[nb_] = __builtin_amdgcn_mfma_f32_16x16x16f16(a[nb_][2], bfr[2], accB_[nb_], 0,0,0); \
    _Pragma("unroll")                                                          \
    for (int nb_ = 0; nb_ < 4; ++nb_)                                          \
        accA_[nb_] = __builtin_amdgcn_mfma_f32_16x16x16f16(a[nb_][1], bfr[1], accA_[nb_], 0,0,0); \
    _Pragma("unroll")                                                          \
    for (int nb_ = 0; nb_ < 4; ++nb_)                                          \
        accB_[nb_] = __builtin_amdgcn_mfma_f32_16x16x16f16(a[nb_][3], bfr[3], accB_[nb_], 0,0,0); \
    const bool pred = (tcur >= tlo) & (tcur < T);                              \
    f32x4 acc_[4];                                                             \
    _Pragma("unroll")                                                          \
    for (int nb_ = 0; nb_ < 4; ++nb_) acc_[nb_] = accA_[nb_] + accB_[nb_];     \
    if (OUTP && pred) {                                                        \
        _Pragma("unroll")                                                      \
        for (int nb_ = 0; nb_ < 4; ++nb_)                                      \
            *(f32x4*)(po + 16*nb_) = acc_[nb_];                                \
    }                                                                          \
    f32x4 nrm[4]; float st = 0.f;                                              \
    _Pragma("unroll")                                                          \
    for (int nb_ = 0; nb_ < 4; ++nb_) {                                        \
        _Pragma("unroll")                                                      \
        for (int r_ = 0; r_ < 4; ++r_) {                                       \
            float z  = fmaf(YCUR, isg_[nb_][r_], nnu_[nb_][r_]);               \
            float ag = fmaf(z*z, -0.72134752f, l2n_[nb_][r_]);                 \
            float g  = __builtin_amdgcn_exp2f(ag);                             \
            nrm[nb_][r_] = acc_[nb_][r_] * g;                                  \
            st += nrm[nb_][r_];                                                \
        }                                                                      \
    }                                                                          \
    st += __shfl_xor(st, 16, 64);                                              \
    st += __shfl_xor(st, 32, 64);                                              \
    const float rs = __builtin_amdgcn_rcpf(st);                                \
    _Pragma("unroll")                                                          \
    for (int nb_ = 0; nb_ < 4; ++nb_) nrm[nb_] *= rs;                          \
    if (OUTP && pred) {                                                        \
        _Pragma("unroll")                                                      \
        for (int nb_ = 0; nb_ < 4; ++nb_)                                      \
            *(f32x4*)(pu + 16*nb_) = nrm[nb_];                                 \
        if (lane < 16) *pf = st;                                               \
    }                                                                          \
    _Pragma("unroll")                                                          \
    for (int kb_ = 0; kb_ < 4; ++kb_) {                                        \
        auto lo_ = __builtin_amdgcn_cvt_pkrtz(nrm[kb_][0], nrm[kb_][1]);       \
        auto hi_ = __builtin_amdgcn_cvt_pkrtz(nrm[kb_][2], nrm[kb_][3]);       \
        bfr[kb_][0] = (_Float16)lo_[0]; bfr[kb_][1] = (_Float16)lo_[1];        \
        bfr[kb_][2] = (_Float16)hi_[0]; bfr[kb_][3] = (_Float16)hi_[1];        \
    }                                                                          \
    if (OUTP) { po += K; pu += K; pf += 1; }                                   \
    ++tcur;                                                                    \
} while (0)

    // burn-in: no stores
#pragma unroll 1
    for (int gi = 0; gi < W_BURN/4; ++gi) {
        int ibn = min(max(tcur + 4, 0), T - 4);
        f32x4 yn = *(const f32x4*)(y + ibn);
        STEP(0, yv[0]); STEP(0, yv[1]); STEP(0, yv[2]); STEP(0, yv[3]);
        yv = yn;
    }
    // first output group (peeled: chunk-0 state override after its t=0 step)
    {
        int ibn = min(max(tcur + 4, 0), T - 4);
        f32x4 yn = *(const f32x4*)(y + ibn);
        STEP(1, yv[0]);
        if (cg == 0) { bfr[0]=u0h[0]; bfr[1]=u0h[1]; bfr[2]=u0h[2]; bfr[3]=u0h[3]; }
        STEP(1, yv[1]); STEP(1, yv[2]); STEP(1, yv[3]);
        yv = yn;
    }
#pragma unroll 1
    for (int gi = 1; gi < S_CHUNK/4; ++gi) {
        int ibn = min(max(tcur + 4, 0), T - 4);
        f32x4 yn = *(const f32x4*)(y + ibn);
        STEP(1, yv[0]); STEP(1, yv[1]); STEP(1, yv[2]); STEP(1, yv[3]);
        yv = yn;
    }
#undef STEP
}

extern "C" void kernel_launch(void* const* d_in, const int* in_sizes, int n_in,
                              void* d_out, int out_size, void* d_ws, size_t ws_size,
                              hipStream_t stream) {
    const float* y      = (const float*)d_in[0];
    const float* logits = (const float*)d_in[1];
    const float* mu     = (const float*)d_in[2];
    const float* lsig   = (const float*)d_in[3];
    float* out = (float*)d_out;
    float* ws  = (float*)d_ws;
    const int T = in_sizes[0];

    hmm_setup<<<1, 64, 0, stream>>>(y, logits, mu, lsig, out, ws, T);

    const int nch  = (T + S_CHUNK - 1) / S_CHUNK;
    const int nblk = (nch + BATCH - 1) / BATCH;
    hmm_scan<<<nblk, 64, 0, stream>>>(y, ws, out, T);
}

// Round 8
// 232.883 us; speedup vs baseline: 1.1551x; 1.0151x over previous
//
#include <hip/hip_runtime.h>

#define K 64
#define S_CHUNK 128
#define W_BURN 160
#define BATCH 16

typedef __attribute__((ext_vector_type(8))) _Float16 half8;
typedef __attribute__((ext_vector_type(4))) float f32x4;
typedef __attribute__((ext_vector_type(4))) int i32x4;

__device__ __forceinline__ float waveReduceSum(float v) {
#pragma unroll
    for (int off = 32; off > 0; off >>= 1) v += __shfl_xor(v, off, 64);
    return v;
}

__device__ __forceinline__ unsigned pkh(float a, float b) {
    auto t = __builtin_amdgcn_cvt_pkrtz(a, b);
    return __builtin_bit_cast(unsigned, t);
}

// ws layout (float offsets)
#define WS_P     0      // P row-major [64][64] f32
#define WS_PI    4096
#define WS_UTT0  4160
#define WS_ISG   4224   // 1/sigma
#define WS_NNU   4288   // -mu/sigma
#define WS_L2N   4352   // log2(1/(sigma*sqrt(2pi)))

__global__ __launch_bounds__(64) void hmm_setup(
    const float* __restrict__ y, const float* __restrict__ logits,
    const float* __restrict__ mu, const float* __restrict__ log_sigma,
    float* __restrict__ out, float* __restrict__ ws, int T)
{
    __shared__ float P[K][K];
    __shared__ float pib[K];
    const int k = threadIdx.x;

    float row[K]; float m = -3.4e38f;
#pragma unroll
    for (int i = 0; i < K; ++i) { row[i] = logits[k*K + i]; m = fmaxf(m, row[i]); }
    float s = 0.f;
#pragma unroll
    for (int i = 0; i < K; ++i) { row[i] = __expf(row[i] - m); s += row[i]; }
    float inv = 1.0f / s;
#pragma unroll
    for (int i = 0; i < K; ++i) { float p = row[i]*inv; P[k][i] = p; ws[WS_P + k*K + i] = p; }
    __syncthreads();

    pib[k] = 1.0f/64.0f;
    __syncthreads();
    for (int it = 0; it < 64; ++it) {
        float acc = 0.f;
#pragma unroll
        for (int j = 0; j < K; ++j) acc += pib[j]*P[j][k];   // (pi^T P)_k
        float tot = waveReduceSum(acc);
        acc /= tot;
        __syncthreads();
        pib[k] = acc;
        __syncthreads();
    }
    float pi_k = pib[k];

    float mu_k = mu[k];
    float isg = __expf(-log_sigma[k]);            // 1/sigma
    float inorm = isg * 0.39894228040143267f;     // 1/(sigma*sqrt(2pi))

    ws[WS_PI  + k] = pi_k;
    ws[WS_ISG + k] = isg;
    ws[WS_NNU + k] = -mu_k * isg;
    ws[WS_L2N + k] = __log2f(inorm);

    float y0 = y[0];
    float z = (y0 - mu_k) * isg;
    float g0 = __expf(-0.5f*z*z) * inorm;
    float num = pi_k * g0;
    float ft0 = waveReduceSum(num);
    float utt0 = num / ft0;
    ws[WS_UTT0 + k] = utt0;

    out[k] = pi_k;                       // ut[0]
    out[(size_t)T*K + k] = utt0;         // unorm[0]
    if (k == 0) out[(size_t)2*T*K] = ft0;// ft[0]
}

// One wave = 16 chunks. gfx950-NATIVE mfma_f32_16x16x32_f16 (8/step).
// R4-R7 evidence: per-SIMD throughput saturated by one wave at ~1900cy/step
// = 16 legacy 16x16x16 MFMAs -> legacy shape ~120cy/instr slow path. K=32
// breaks the C/D==B-frag identity, so beta is redistributed per step with
// 16 ds_bpermute + 8 cndmask (exact, no precision cost):
//   B[kb] j=0..3 <- nrm[2kb+(q>>1)] @ lane 32(q&1)+c ; j=4..7 <- +16 lane.
__global__ __launch_bounds__(64, 1) void hmm_scan(
    const float* __restrict__ y, const float* __restrict__ ws,
    float* __restrict__ out, int T)
{
    const int lane = threadIdx.x;
    const int c = lane & 15;          // chunk slot / matrix column
    const int q = lane >> 4;          // lane group
    const int cg = blockIdx.x * BATCH + c;
    const int t0 = cg * S_CHUNK;

    // A fragments (16x16x32): lane 16q+c holds A row c (state 16nb+c),
    // k = 8q+j within kb-block: a[nb][kb][j] = P[32kb+8q+j][16nb+c]
    half8 a[4][2];
#pragma unroll
    for (int nb = 0; nb < 4; ++nb)
#pragma unroll
        for (int kb = 0; kb < 2; ++kb)
#pragma unroll
            for (int j = 0; j < 8; ++j)
                a[nb][kb][j] = (_Float16)ws[WS_P + (32*kb + 8*q + j)*K + 16*nb + c];

    // emission constants (C/D layout): s = 16nb + 4q + r
    f32x4 isg_[4], nnu_[4], l2n_[4];
#pragma unroll
    for (int nb = 0; nb < 4; ++nb)
#pragma unroll
        for (int r = 0; r < 4; ++r) {
            int s = 16*nb + 4*q + r;
            isg_[nb][r] = ws[WS_ISG + s];
            nnu_[nb][r] = ws[WS_NNU + s];
            l2n_[nb][r] = ws[WS_L2N + s];
        }

    // B fragments: bfr[kb][j] = beta[32kb + 8q + j] of chunk c
    half8 bfr[2], u0h[2];
#pragma unroll
    for (int kb = 0; kb < 2; ++kb)
#pragma unroll
        for (int j = 0; j < 8; ++j) {
            int s = 32*kb + 8*q + j;
            bfr[kb][j] = (_Float16)ws[WS_PI + s];
            u0h[kb][j] = (_Float16)ws[WS_UTT0 + s];
        }

    const int tlo = (cg == 0) ? 1 : 0;
    int tcur = t0 - W_BURN;

    float* po = out + (size_t)t0 * K + 4*q;
    float* pu = po + (size_t)T * K;
    float* pf = out + (size_t)2 * T * K + t0;

    // bpermute byte addresses: src lane 32*(q&1)+c and +16
    const int ad0 = (((lane & 16) << 1) | (lane & 15)) << 2;
    const int ad1 = ad0 + 64;
    const bool hi = (lane >= 32);   // q>>1

    int ib = min(max(tcur, 0), T - 4);
    f32x4 yv = *(const f32x4*)(y + ib);

#define STEP(OUTP, YCUR) do {                                                  \
    f32x4 acc_[4] = {{0.f,0.f,0.f,0.f},{0.f,0.f,0.f,0.f},                      \
                     {0.f,0.f,0.f,0.f},{0.f,0.f,0.f,0.f}};                     \
    _Pragma("unroll")                                                          \
    for (int nb_ = 0; nb_ < 4; ++nb_)                                          \
        acc_[nb_] = __builtin_amdgcn_mfma_f32_16x16x32_f16(a[nb_][0], bfr[0], acc_[nb_], 0,0,0); \
    _Pragma("unroll")                                                          \
    for (int nb_ = 0; nb_ < 4; ++nb_)                                          \
        acc_[nb_] = __builtin_amdgcn_mfma_f32_16x16x32_f16(a[nb_][1], bfr[1], acc_[nb_], 0,0,0); \
    const bool pred = (tcur >= tlo) & (tcur < T);                              \
    if (OUTP && pred) {                                                        \
        _Pragma("unroll")                                                      \
        for (int nb_ = 0; nb_ < 4; ++nb_)                                      \
            *(f32x4*)(po + 16*nb_) = acc_[nb_];                                \
    }                                                                          \
    f32x4 nrm[4]; float st = 0.f;                                              \
    _Pragma("unroll")                                                          \
    for (int nb_ = 0; nb_ < 4; ++nb_) {                                        \
        _Pragma("unroll")                                                      \
        for (int r_ = 0; r_ < 4; ++r_) {                                       \
            float z  = fmaf(YCUR, isg_[nb_][r_], nnu_[nb_][r_]);               \
            float ag = fmaf(z*z, -0.72134752f, l2n_[nb_][r_]);                 \
            float g  = __builtin_amdgcn_exp2f(ag);                             \
            nrm[nb_][r_] = acc_[nb_][r_] * g;                                  \
            st += nrm[nb_][r_];                                                \
        }                                                                      \
    }                                                                          \
    st += __shfl_xor(st, 16, 64);                                              \
    st += __shfl_xor(st, 32, 64);                                              \
    const float rs = __builtin_amdgcn_rcpf(st);                                \
    _Pragma("unroll")                                                          \
    for (int nb_ = 0; nb_ < 4; ++nb_) nrm[nb_] *= rs;                          \
    if (OUTP && pred) {                                                        \
        _Pragma("unroll")                                                      \
        for (int nb_ = 0; nb_ < 4; ++nb_)                                      \
            *(f32x4*)(pu + 16*nb_) = nrm[nb_];                                 \
        if (lane < 16) *pf = st;                                               \
    }                                                                          \
    /* pack normalized beta to f16 words: pk[nb] = {r0r1, r2r3} */             \
    unsigned p0w0 = pkh(nrm[0][0], nrm[0][1]), p0w1 = pkh(nrm[0][2], nrm[0][3]); \
    unsigned p1w0 = pkh(nrm[1][0], nrm[1][1]), p1w1 = pkh(nrm[1][2], nrm[1][3]); \
    unsigned p2w0 = pkh(nrm[2][0], nrm[2][1]), p2w1 = pkh(nrm[2][2], nrm[2][3]); \
    unsigned p3w0 = pkh(nrm[3][0], nrm[3][1]), p3w1 = pkh(nrm[3][2], nrm[3][3]); \
    /* redistribute C/D -> B layout: 16 bpermute + 8 select */                 \
    int qA0 = __builtin_amdgcn_ds_bpermute(ad0, (int)p0w0);                    \
    int qA1 = __builtin_amdgcn_ds_bpermute(ad0, (int)p0w1);                    \
    int qB0 = __builtin_amdgcn_ds_bpermute(ad0, (int)p1w0);                    \
    int qB1 = __builtin_amdgcn_ds_bpermute(ad0, (int)p1w1);                    \
    int qA2 = __builtin_amdgcn_ds_bpermute(ad1, (int)p0w0);                    \
    int qA3 = __builtin_amdgcn_ds_bpermute(ad1, (int)p0w1);                    \
    int qB2 = __builtin_amdgcn_ds_bpermute(ad1, (int)p1w0);                    \
    int qB3 = __builtin_amdgcn_ds_bpermute(ad1, (int)p1w1);                    \
    int rA0 = __builtin_amdgcn_ds_bpermute(ad0, (int)p2w0);                    \
    int rA1 = __builtin_amdgcn_ds_bpermute(ad0, (int)p2w1);                    \
    int rB0 = __builtin_amdgcn_ds_bpermute(ad0, (int)p3w0);                    \
    int rB1 = __builtin_amdgcn_ds_bpermute(ad0, (int)p3w1);                    \
    int rA2 = __builtin_amdgcn_ds_bpermute(ad1, (int)p2w0);                    \
    int rA3 = __builtin_amdgcn_ds_bpermute(ad1, (int)p2w1);                    \
    int rB2 = __builtin_amdgcn_ds_bpermute(ad1, (int)p3w0);                    \
    int rB3 = __builtin_amdgcn_ds_bpermute(ad1, (int)p3w1);                    \
    i32x4 w0_ = { hi ? qB0 : qA0, hi ? qB1 : qA1,                              \
                  hi ? qB2 : qA2, hi ? qB3 : qA3 };                            \
    i32x4 w1_ = { hi ? rB0 : rA0, hi ? rB1 : rA1,                              \
                  hi ? rB2 : rA2, hi ? rB3 : rA3 };                            \
    bfr[0] = __builtin_bit_cast(half8, w0_);                                   \
    bfr[1] = __builtin_bit_cast(half8, w1_);                                   \
    if (OUTP) { po += K; pu += K; pf += 1; }                                   \
    ++tcur;                                                                    \
} while (0)

    // burn-in: no stores
#pragma unroll 1
    for (int gi = 0; gi < W_BURN/4; ++gi) {
        int ibn = min(max(tcur + 4, 0), T - 4);
        f32x4 yn = *(const f32x4*)(y + ibn);
        STEP(0, yv[0]); STEP(0, yv[1]); STEP(0, yv[2]); STEP(0, yv[3]);
        yv = yn;
    }
    // first output group (peeled: chunk-0 state override after its t=0 step)
    {
        int ibn = min(max(tcur + 4, 0), T - 4);
        f32x4 yn = *(const f32x4*)(y + ibn);
        STEP(1, yv[0]);
        if (cg == 0) { bfr[0] = u0h[0]; bfr[1] = u0h[1]; }
        STEP(1, yv[1]); STEP(1, yv[2]); STEP(1, yv[3]);
        yv = yn;
    }
#pragma unroll 1
    for (int gi = 1; gi < S_CHUNK/4; ++gi) {
        int ibn = min(max(tcur + 4, 0), T - 4);
        f32x4 yn = *(const f32x4*)(y + ibn);
        STEP(1, yv[0]); STEP(1, yv[1]); STEP(1, yv[2]); STEP(1, yv[3]);
        yv = yn;
    }
#undef STEP
}

extern "C" void kernel_launch(void* const* d_in, const int* in_sizes, int n_in,
                              void* d_out, int out_size, void* d_ws, size_t ws_size,
                              hipStream_t stream) {
    const float* y      = (const float*)d_in[0];
    const float* logits = (const float*)d_in[1];
    const float* mu     = (const float*)d_in[2];
    const float* lsig   = (const float*)d_in[3];
    float* out = (float*)d_out;
    float* ws  = (float*)d_ws;
    const int T = in_sizes[0];

    hmm_setup<<<1, 64, 0, stream>>>(y, logits, mu, lsig, out, ws, T);

    const int nch  = (T + S_CHUNK - 1) / S_CHUNK;
    const int nblk = (nch + BATCH - 1) / BATCH;
    hmm_scan<<<nblk, 64, 0, stream>>>(y, ws, out, T);
}

// Round 9
// 226.142 us; speedup vs baseline: 1.1896x; 1.0298x over previous
//
#include <hip/hip_runtime.h>

#define K 64
#define S_CHUNK 64
#define W_BURN 128
#define BATCH 16

typedef __attribute__((ext_vector_type(8))) _Float16 half8;
typedef __attribute__((ext_vector_type(4))) float f32x4;
typedef __attribute__((ext_vector_type(4))) int i32x4;

__device__ __forceinline__ float waveReduceSum(float v) {
#pragma unroll
    for (int off = 32; off > 0; off >>= 1) v += __shfl_xor(v, off, 64);
    return v;
}

__device__ __forceinline__ unsigned pkh(float a, float b) {
    auto t = __builtin_amdgcn_cvt_pkrtz(a, b);
    return __builtin_bit_cast(unsigned, t);
}

// ws layout (float offsets)
#define WS_P     0      // P row-major [64][64] f32
#define WS_PI    4096
#define WS_UTT0  4160
#define WS_ISG   4224   // 1/sigma
#define WS_NNU   4288   // -mu/sigma
#define WS_L2N   4352   // log2(1/(sigma*sqrt(2pi)))

__global__ __launch_bounds__(64) void hmm_setup(
    const float* __restrict__ y, const float* __restrict__ logits,
    const float* __restrict__ mu, const float* __restrict__ log_sigma,
    float* __restrict__ out, float* __restrict__ ws, int T)
{
    __shared__ float P[K][K];
    __shared__ float pib[K];
    const int k = threadIdx.x;

    float row[K]; float m = -3.4e38f;
#pragma unroll
    for (int i = 0; i < K; ++i) { row[i] = logits[k*K + i]; m = fmaxf(m, row[i]); }
    float s = 0.f;
#pragma unroll
    for (int i = 0; i < K; ++i) { row[i] = __expf(row[i] - m); s += row[i]; }
    float inv = 1.0f / s;
#pragma unroll
    for (int i = 0; i < K; ++i) { float p = row[i]*inv; P[k][i] = p; ws[WS_P + k*K + i] = p; }
    __syncthreads();

    pib[k] = 1.0f/64.0f;
    __syncthreads();
    for (int it = 0; it < 64; ++it) {
        float acc = 0.f;
#pragma unroll
        for (int j = 0; j < K; ++j) acc += pib[j]*P[j][k];   // (pi^T P)_k
        float tot = waveReduceSum(acc);
        acc /= tot;
        __syncthreads();
        pib[k] = acc;
        __syncthreads();
    }
    float pi_k = pib[k];

    float mu_k = mu[k];
    float isg = __expf(-log_sigma[k]);            // 1/sigma
    float inorm = isg * 0.39894228040143267f;     // 1/(sigma*sqrt(2pi))

    ws[WS_PI  + k] = pi_k;
    ws[WS_ISG + k] = isg;
    ws[WS_NNU + k] = -mu_k * isg;
    ws[WS_L2N + k] = __log2f(inorm);

    float y0 = y[0];
    float z = (y0 - mu_k) * isg;
    float g0 = __expf(-0.5f*z*z) * inorm;
    float num = pi_k * g0;
    float ft0 = waveReduceSum(num);
    float utt0 = num / ft0;
    ws[WS_UTT0 + k] = utt0;

    out[k] = pi_k;                       // ut[0]
    out[(size_t)T*K + k] = utt0;         // unorm[0]
    if (k == 0) out[(size_t)2*T*K] = ft0;// ft[0]
}

// One wave = 16 chunks, gfx950-native mfma_f32_16x16x32_f16 (8/step) with
// ds_bpermute C/D->B redistribution. R4-R8 established: per-wave step time
// is pinned at ~790ns regardless of micro-structure, and per-SIMD step
// throughput saturates at 1 wave. Therefore minimize steps/wave subject to
// all waves co-resident at <=1 wave/SIMD:
//   S_CHUNK=64 -> 977 waves (0.95/SIMD), W_BURN=128 (R1-proven residual
//   ~2e-3), steps/wave = 192 vs 288.  Wall = 192 x step_time.
__global__ __launch_bounds__(64, 1) void hmm_scan(
    const float* __restrict__ y, const float* __restrict__ ws,
    float* __restrict__ out, int T)
{
    const int lane = threadIdx.x;
    const int c = lane & 15;          // chunk slot / matrix column
    const int q = lane >> 4;          // lane group
    const int cg = blockIdx.x * BATCH + c;
    const int t0 = cg * S_CHUNK;

    // A fragments (16x16x32): lane 16q+c holds A row c (state 16nb+c),
    // k = 8q+j within kb-block: a[nb][kb][j] = P[32kb+8q+j][16nb+c]
    half8 a[4][2];
#pragma unroll
    for (int nb = 0; nb < 4; ++nb)
#pragma unroll
        for (int kb = 0; kb < 2; ++kb)
#pragma unroll
            for (int j = 0; j < 8; ++j)
                a[nb][kb][j] = (_Float16)ws[WS_P + (32*kb + 8*q + j)*K + 16*nb + c];

    // emission constants (C/D layout): s = 16nb + 4q + r
    f32x4 isg_[4], nnu_[4], l2n_[4];
#pragma unroll
    for (int nb = 0; nb < 4; ++nb)
#pragma unroll
        for (int r = 0; r < 4; ++r) {
            int s = 16*nb + 4*q + r;
            isg_[nb][r] = ws[WS_ISG + s];
            nnu_[nb][r] = ws[WS_NNU + s];
            l2n_[nb][r] = ws[WS_L2N + s];
        }

    // B fragments: bfr[kb][j] = beta[32kb + 8q + j] of chunk c
    half8 bfr[2], u0h[2];
#pragma unroll
    for (int kb = 0; kb < 2; ++kb)
#pragma unroll
        for (int j = 0; j < 8; ++j) {
            int s = 32*kb + 8*q + j;
            bfr[kb][j] = (_Float16)ws[WS_PI + s];
            u0h[kb][j] = (_Float16)ws[WS_UTT0 + s];
        }

    const int tlo = (cg == 0) ? 1 : 0;
    int tcur = t0 - W_BURN;

    float* po = out + (size_t)t0 * K + 4*q;
    float* pu = po + (size_t)T * K;
    float* pf = out + (size_t)2 * T * K + t0;

    // bpermute byte addresses: src lane 32*(q&1)+c and +16
    const int ad0 = (((lane & 16) << 1) | (lane & 15)) << 2;
    const int ad1 = ad0 + 64;
    const bool hi = (lane >= 32);   // q>>1

    int ib = min(max(tcur, 0), T - 4);
    f32x4 yv = *(const f32x4*)(y + ib);

#define STEP(OUTP, YCUR) do {                                                  \
    f32x4 acc_[4] = {{0.f,0.f,0.f,0.f},{0.f,0.f,0.f,0.f},                      \
                     {0.f,0.f,0.f,0.f},{0.f,0.f,0.f,0.f}};                     \
    _Pragma("unroll")                                                          \
    for (int nb_ = 0; nb_ < 4; ++nb_)                                          \
        acc_[nb_] = __builtin_amdgcn_mfma_f32_16x16x32_f16(a[nb_][0], bfr[0], acc_[nb_], 0,0,0); \
    _Pragma("unroll")                                                          \
    for (int nb_ = 0; nb_ < 4; ++nb_)                                          \
        acc_[nb_] = __builtin_amdgcn_mfma_f32_16x16x32_f16(a[nb_][1], bfr[1], acc_[nb_], 0,0,0); \
    const bool pred = (tcur >= tlo) & (tcur < T);                              \
    if (OUTP && pred) {                                                        \
        _Pragma("unroll")                                                      \
        for (int nb_ = 0; nb_ < 4; ++nb_)                                      \
            *(f32x4*)(po + 16*nb_) = acc_[nb_];                                \
    }                                                                          \
    f32x4 nrm[4]; float st = 0.f;                                              \
    _Pragma("unroll")                                                          \
    for (int nb_ = 0; nb_ < 4; ++nb_) {                                        \
        _Pragma("unroll")                                                      \
        for (int r_ = 0; r_ < 4; ++r_) {                                       \
            float z  = fmaf(YCUR, isg_[nb_][r_], nnu_[nb_][r_]);               \
            float ag = fmaf(z*z, -0.72134752f, l2n_[nb_][r_]);                 \
            float g  = __builtin_amdgcn_exp2f(ag);                             \
            nrm[nb_][r_] = acc_[nb_][r_] * g;                                  \
            st += nrm[nb_][r_];                                                \
        }                                                                      \
    }                                                                          \
    st += __shfl_xor(st, 16, 64);                                              \
    st += __shfl_xor(st, 32, 64);                                              \
    const float rs = __builtin_amdgcn_rcpf(st);                                \
    _Pragma("unroll")                                                          \
    for (int nb_ = 0; nb_ < 4; ++nb_) nrm[nb_] *= rs;                          \
    if (OUTP && pred) {                                                        \
        _Pragma("unroll")                                                      \
        for (int nb_ = 0; nb_ < 4; ++nb_)                                      \
            *(f32x4*)(pu + 16*nb_) = nrm[nb_];                                 \
        if (lane < 16) *pf = st;                                               \
    }                                                                          \
    /* pack normalized beta to f16 words: pk[nb] = {r0r1, r2r3} */             \
    unsigned p0w0 = pkh(nrm[0][0], nrm[0][1]), p0w1 = pkh(nrm[0][2], nrm[0][3]); \
    unsigned p1w0 = pkh(nrm[1][0], nrm[1][1]), p1w1 = pkh(nrm[1][2], nrm[1][3]); \
    unsigned p2w0 = pkh(nrm[2][0], nrm[2][1]), p2w1 = pkh(nrm[2][2], nrm[2][3]); \
    unsigned p3w0 = pkh(nrm[3][0], nrm[3][1]), p3w1 = pkh(nrm[3][2], nrm[3][3]); \
    /* redistribute C/D -> B layout: 16 bpermute + 8 select */                 \
    int qA0 = __builtin_amdgcn_ds_bpermute(ad0, (int)p0w0);                    \
    int qA1 = __builtin_amdgcn_ds_bpermute(ad0, (int)p0w1);                    \
    int qB0 = __builtin_amdgcn_ds_bpermute(ad0, (int)p1w0);                    \
    int qB1 = __builtin_amdgcn_ds_bpermute(ad0, (int)p1w1);                    \
    int qA2 = __builtin_amdgcn_ds_bpermute(ad1, (int)p0w0);                    \
    int qA3 = __builtin_amdgcn_ds_bpermute(ad1, (int)p0w1);                    \
    int qB2 = __builtin_amdgcn_ds_bpermute(ad1, (int)p1w0);                    \
    int qB3 = __builtin_amdgcn_ds_bpermute(ad1, (int)p1w1);                    \
    int rA0 = __builtin_amdgcn_ds_bpermute(ad0, (int)p2w0);                    \
    int rA1 = __builtin_amdgcn_ds_bpermute(ad0, (int)p2w1);                    \
    int rB0 = __builtin_amdgcn_ds_bpermute(ad0, (int)p3w0);                    \
    int rB1 = __builtin_amdgcn_ds_bpermute(ad0, (int)p3w1);                    \
    int rA2 = __builtin_amdgcn_ds_bpermute(ad1, (int)p2w0);                    \
    int rA3 = __builtin_amdgcn_ds_bpermute(ad1, (int)p2w1);                    \
    int rB2 = __builtin_amdgcn_ds_bpermute(ad1, (int)p3w0);                    \
    int rB3 = __builtin_amdgcn_ds_bpermute(ad1, (int)p3w1);                    \
    i32x4 w0_ = { hi ? qB0 : qA0, hi ? qB1 : qA1,                              \
                  hi ? qB2 : qA2, hi ? qB3 : qA3 };                            \
    i32x4 w1_ = { hi ? rB0 : rA0, hi ? rB1 : rA1,                              \
                  hi ? rB2 : rA2, hi ? rB3 : rA3 };                            \
    bfr[0] = __builtin_bit_cast(half8, w0_);                                   \
    bfr[1] = __builtin_bit_cast(half8, w1_);                                   \
    if (OUTP) { po += K; pu += K; pf += 1; }                                   \
    ++tcur;                                                                    \
} while (0)

    // burn-in: no stores
#pragma unroll 1
    for (int gi = 0; gi < W_BURN/4; ++gi) {
        int ibn = min(max(tcur + 4, 0), T - 4);
        f32x4 yn = *(const f32x4*)(y + ibn);
        STEP(0, yv[0]); STEP(0, yv[1]); STEP(0, yv[2]); STEP(0, yv[3]);
        yv = yn;
    }
    // first output group (peeled: chunk-0 state override after its t=0 step)
    {
        int ibn = min(max(tcur + 4, 0), T - 4);
        f32x4 yn = *(const f32x4*)(y + ibn);
        STEP(1, yv[0]);
        if (cg == 0) { bfr[0] = u0h[0]; bfr[1] = u0h[1]; }
        STEP(1, yv[1]); STEP(1, yv[2]); STEP(1, yv[3]);
        yv = yn;
    }
#pragma unroll 1
    for (int gi = 1; gi < S_CHUNK/4; ++gi) {
        int ibn = min(max(tcur + 4, 0), T - 4);
        f32x4 yn = *(const f32x4*)(y + ibn);
        STEP(1, yv[0]); STEP(1, yv[1]); STEP(1, yv[2]); STEP(1, yv[3]);
        yv = yn;
    }
#undef STEP
}

extern "C" void kernel_launch(void* const* d_in, const int* in_sizes, int n_in,
                              void* d_out, int out_size, void* d_ws, size_t ws_size,
                              hipStream_t stream) {
    const float* y      = (const float*)d_in[0];
    const float* logits = (const float*)d_in[1];
    const float* mu     = (const float*)d_in[2];
    const float* lsig   = (const float*)d_in[3];
    float* out = (float*)d_out;
    float* ws  = (float*)d_ws;
    const int T = in_sizes[0];

    hmm_setup<<<1, 64, 0, stream>>>(y, logits, mu, lsig, out, ws, T);

    const int nch  = (T + S_CHUNK - 1) / S_CHUNK;
    const int nblk = (nch + BATCH - 1) / BATCH;
    hmm_scan<<<nblk, 64, 0, stream>>>(y, ws, out, T);
}